// Round 3
// baseline (4565.535 us; speedup 1.0000x reference)
//
#include <hip/hip_runtime.h>

#define NN    60000
#define NODES 100000
#define DD    64
#define NNZ   3200000
#define BB    1024
#define NEG   0.2f
#define RPB   256                        // rows per bucket
#define NBUCK 391                        // ceil(NODES/RPB)
#define EPB   8192                       // edges per sort block
#define NPB   ((NNZ + EPB - 1) / EPB)    // 391

// ---------------------------------------------------------------- init x = concat(eu, ei)
__global__ __launch_bounds__(256) void k_init_x(const float* __restrict__ eu,
                                                const float* __restrict__ ei,
                                                float* __restrict__ x) {
    int i = blockIdx.x * 256 + threadIdx.x;          // float4 index
    const int TOT = NODES * DD / 4;
    if (i >= TOT) return;
    const int UE = NN * DD / 4;
    float4 v = (i < UE) ? ((const float4*)eu)[i] : ((const float4*)ei)[i - UE];
    ((float4*)x)[i] = v;
}

// ---------------------------------------------------------------- bucket counts
__global__ __launch_bounds__(512) void k_cnt(const int* __restrict__ row,
                                             int* __restrict__ gbcount) {
    __shared__ int h[NBUCK];
    int t = threadIdx.x;
    if (t < NBUCK) h[t] = 0;
    __syncthreads();
    int base = blockIdx.x * EPB;
    int n = min(EPB, NNZ - base);
    for (int k = t; k < n; k += 512) atomicAdd(&h[row[base + k] >> 8], 1);
    __syncthreads();
    if (t < NBUCK && h[t]) atomicAdd(&gbcount[t], h[t]);
}

// ---------------------------------------------------------------- bucket offsets (1 block)
__global__ __launch_bounds__(512) void k_bscan(const int* __restrict__ gbcount,
                                               int* __restrict__ boff,
                                               int* __restrict__ gcur) {
    __shared__ int s[512];
    int t = threadIdx.x;
    int v = (t < NBUCK) ? gbcount[t] : 0;
    s[t] = v;
    __syncthreads();
    for (int off = 1; off < 512; off <<= 1) {
        int u = (t >= off) ? s[t - off] : 0;
        __syncthreads();
        s[t] += u;
        __syncthreads();
    }
    int ex = s[t] - v;
    if (t < NBUCK) { boff[t] = ex; gcur[t] = ex; }
    if (t == NBUCK) boff[NBUCK] = ex;   // == NNZ
}

// ---------------------------------------------------------------- bucket sort with
// block-local LDS counting sort -> contiguous ascending global write runs
__global__ __launch_bounds__(512) void k_place(const int* __restrict__ row,
                                               const int* __restrict__ col,
                                               const float* __restrict__ val,
                                               int* __restrict__ gcur,
                                               int2* __restrict__ bulk) {
    __shared__ int rows_l[EPB];                // 32 KB
    __shared__ unsigned short perm[EPB];       // 16 KB
    __shared__ int h[NBUCK], bloc[NBUCK], bcur[NBUCK], gseg[NBUCK];
    __shared__ int sc[512];
    int t = threadIdx.x;
    if (t < NBUCK) h[t] = 0;
    __syncthreads();
    int base = blockIdx.x * EPB;
    int n = min(EPB, NNZ - base);
    for (int k = t; k < n; k += 512) {
        int r = row[base + k];
        rows_l[k] = r;
        atomicAdd(&h[r >> 8], 1);
    }
    __syncthreads();
    // block-local exclusive scan over buckets + global segment reservation
    {
        int v = (t < NBUCK) ? h[t] : 0;
        sc[t] = v;
        __syncthreads();
        for (int off = 1; off < 512; off <<= 1) {
            int u = (t >= off) ? sc[t - off] : 0;
            __syncthreads();
            sc[t] += u;
            __syncthreads();
        }
        if (t < NBUCK) {
            int ex = sc[t] - v;
            bloc[t] = ex;
            bcur[t] = ex;
            gseg[t] = v ? atomicAdd(&gcur[t], v) : 0;
        }
    }
    __syncthreads();
    for (int k = t; k < n; k += 512) {
        int p = atomicAdd(&bcur[rows_l[k] >> 8], 1);
        perm[p] = (unsigned short)k;
    }
    __syncthreads();
    // write out in block-sorted order: ascending addresses within each segment
    for (int j = t; j < n; j += 512) {
        int k = perm[j];
        int r = rows_l[k];
        int b8 = r >> 8;
        int addr = gseg[b8] + (j - bloc[b8]);
        bulk[addr] = make_int2(((r & 255) << 17) | col[base + k],
                               __float_as_int(val[base + k]));
    }
}

// ---------------------------------------------------------------- push SpMM: 1 block/bucket,
// LDS fp32 accumulator (256 rows x 64 dims = 64 KB), single-writer output region
__global__ __launch_bounds__(1024) void k_pspmm(const int* __restrict__ boff,
                                                const int2* __restrict__ bulk,
                                                const float* __restrict__ x,
                                                float* __restrict__ lie) {
    __shared__ float acc[RPB * DD];            // 64 KB
    int t = threadIdx.x;
    float4* av = (float4*)acc;
    for (int i = t; i < RPB * DD / 4; i += 1024) av[i] = make_float4(0.f, 0.f, 0.f, 0.f);
    __syncthreads();
    int b = blockIdx.x;
    int s = boff[b], e = boff[b + 1];
    int lane = t & 63, wid = t >> 6;
    for (int base = s + wid * 64; base < e; base += 16 * 64) {
        int n = min(64, e - base);
        int2 ed = make_int2(0, 0);
        if (lane < n) ed = bulk[base + lane];
        int j = 0;
        for (; j + 4 <= n; j += 4) {
            int e0 = __shfl(ed.x, j),     e1 = __shfl(ed.x, j + 1);
            int e2 = __shfl(ed.x, j + 2), e3 = __shfl(ed.x, j + 3);
            float v0 = __int_as_float(__shfl(ed.y, j));
            float v1 = __int_as_float(__shfl(ed.y, j + 1));
            float v2 = __int_as_float(__shfl(ed.y, j + 2));
            float v3 = __int_as_float(__shfl(ed.y, j + 3));
            float x0 = x[(e0 & 0x1FFFF) * DD + lane];
            float x1 = x[(e1 & 0x1FFFF) * DD + lane];
            float x2 = x[(e2 & 0x1FFFF) * DD + lane];
            float x3 = x[(e3 & 0x1FFFF) * DD + lane];
            atomicAdd(&acc[(e0 >> 17) * DD + lane], v0 * x0);
            atomicAdd(&acc[(e1 >> 17) * DD + lane], v1 * x1);
            atomicAdd(&acc[(e2 >> 17) * DD + lane], v2 * x2);
            atomicAdd(&acc[(e3 >> 17) * DD + lane], v3 * x3);
        }
        for (; j < n; ++j) {
            int e0 = __shfl(ed.x, j);
            float v0 = __int_as_float(__shfl(ed.y, j));
            float x0 = x[(e0 & 0x1FFFF) * DD + lane];
            atomicAdd(&acc[(e0 >> 17) * DD + lane], v0 * x0);
        }
    }
    __syncthreads();
    int row0 = b * RPB;
    for (int i = t; i < RPB * DD / 4; i += 1024) {
        int gr = row0 + (i >> 4);
        if (gr < NODES) ((float4*)lie)[gr * 16 + (i & 15)] = av[i];
    }
}

// ---------------------------------------------------------------- fused layer GEMM
__global__ __launch_bounds__(256) void k_gemm(float* __restrict__ x,
                                              const float* __restrict__ lie,
                                              const float* __restrict__ W1,
                                              const float* __restrict__ W2,
                                              const float* __restrict__ b1,
                                              const float* __restrict__ b2) {
    __shared__ float A1[64 * 64];
    __shared__ float A2[64 * 64];
    __shared__ float Ws1[64 * 64];
    __shared__ float Ws2[64 * 64];

    const int t = threadIdx.x;
    const int row0 = blockIdx.x * 64;

    {
        const float4* w1v = (const float4*)W1;
        const float4* w2v = (const float4*)W2;
        float4* s1v = (float4*)Ws1;
        float4* s2v = (float4*)Ws2;
#pragma unroll
        for (int q = 0; q < 4; ++q) {
            s1v[q * 256 + t] = w1v[q * 256 + t];
            s2v[q * 256 + t] = w2v[q * 256 + t];
        }
    }
#pragma unroll
    for (int q = 0; q < 4; ++q) {
        int f4 = q * 256 + t;
        int rl = f4 >> 4;
        int c4 = f4 & 15;
        int gr = row0 + rl;
        float4 lv = make_float4(0.f, 0.f, 0.f, 0.f);
        float4 xv = make_float4(0.f, 0.f, 0.f, 0.f);
        if (gr < NODES) {
            lv = *(const float4*)&lie[gr * DD + c4 * 4];
            xv = *(const float4*)&x[gr * DD + c4 * 4];
        }
        int sg = c4 ^ (rl & 15);
        ((float4*)A1)[rl * 16 + sg] = lv;
        ((float4*)A2)[rl * 16 + sg] = make_float4(lv.x * xv.x, lv.y * xv.y,
                                                  lv.z * xv.z, lv.w * xv.w);
    }
    __syncthreads();

    const int tx = t & 15;
    const int ty = t >> 4;
    float bs[4];
    {
        float4 bb1 = *(const float4*)&b1[tx * 4];
        float4 bb2 = *(const float4*)&b2[tx * 4];
        bs[0] = bb1.x + bb2.x; bs[1] = bb1.y + bb2.y;
        bs[2] = bb1.z + bb2.z; bs[3] = bb1.w + bb2.w;
    }
    float acc[4][4];
#pragma unroll
    for (int i = 0; i < 4; ++i)
#pragma unroll
        for (int j = 0; j < 4; ++j) acc[i][j] = bs[j];

    for (int k4 = 0; k4 < 16; ++k4) {
        float4 a1[4], a2[4];
#pragma unroll
        for (int i = 0; i < 4; ++i) {
            int r = ty * 4 + i;
            int sg = k4 ^ (r & 15);
            a1[i] = ((const float4*)A1)[r * 16 + sg];
            a2[i] = ((const float4*)A2)[r * 16 + sg];
        }
#pragma unroll
        for (int kk = 0; kk < 4; ++kk) {
            float4 w1 = ((const float4*)Ws1)[(k4 * 4 + kk) * 16 + tx];
            float4 w2 = ((const float4*)Ws2)[(k4 * 4 + kk) * 16 + tx];
#pragma unroll
            for (int i = 0; i < 4; ++i) {
                float av1 = (&a1[i].x)[kk];
                float av2 = (&a2[i].x)[kk];
                acc[i][0] = fmaf(av1, w1.x, fmaf(av2, w2.x, acc[i][0]));
                acc[i][1] = fmaf(av1, w1.y, fmaf(av2, w2.y, acc[i][1]));
                acc[i][2] = fmaf(av1, w1.z, fmaf(av2, w2.z, acc[i][2]));
                acc[i][3] = fmaf(av1, w1.w, fmaf(av2, w2.w, acc[i][3]));
            }
        }
    }
#pragma unroll
    for (int i = 0; i < 4; ++i) {
        int gr = row0 + ty * 4 + i;
        if (gr < NODES) {
            float4 o;
            o.x = acc[i][0] >= 0.f ? acc[i][0] : NEG * acc[i][0];
            o.y = acc[i][1] >= 0.f ? acc[i][1] : NEG * acc[i][1];
            o.z = acc[i][2] >= 0.f ? acc[i][2] : NEG * acc[i][2];
            o.w = acc[i][3] >= 0.f ? acc[i][3] : NEG * acc[i][3];
            *(float4*)&x[gr * DD + tx * 4] = o;
        }
    }
}

// ---------------------------------------------------------------- gather layer repr into output
__global__ __launch_bounds__(256) void k_gather(const float* __restrict__ x,
                                                const int* __restrict__ su,
                                                const int* __restrict__ oi,
                                                const int* __restrict__ ui,
                                                float* __restrict__ out, int layer) {
    int w    = (blockIdx.x * 256 + threadIdx.x) >> 6;
    int lane = threadIdx.x & 63;
    if (w >= 3 * BB) return;
    int g = w >> 10, b = w & 1023;
    int node = (g == 0) ? su[b] : (NN + ((g == 1) ? oi[b] : ui[b]));
    out[w * 256 + layer * 64 + lane] = x[node * DD + lane];
}

// ---------------------------------------------------------------- launch
extern "C" void kernel_launch(void* const* d_in, const int* in_sizes, int n_in,
                              void* d_out, int out_size, void* d_ws, size_t ws_size,
                              hipStream_t stream) {
    const int*   edge_row = (const int*)d_in[0];
    const int*   edge_col = (const int*)d_in[1];
    const float* edge_val = (const float*)d_in[2];
    const float* eu = (const float*)d_in[3];
    const float* ei = (const float*)d_in[4];
    const float* W1 = (const float*)d_in[5];
    const float* W2 = (const float*)d_in[6];
    const float* b1 = (const float*)d_in[7];
    const float* b2 = (const float*)d_in[8];
    const int*   su = (const int*)d_in[9];
    const int*   oi = (const int*)d_in[10];
    const int*   ui = (const int*)d_in[11];
    float* out = (float*)d_out;

    // workspace carve (~76.8 MB)
    float* x       = (float*)d_ws;                 // 6.4M f
    float* lie     = x + NODES * DD;               // 6.4M f
    int2*  bulk    = (int2*)(lie + NODES * DD);    // NNZ int2
    int*   gbcount = (int*)(bulk + NNZ);           // NBUCK
    int*   boff    = gbcount + NBUCK;              // NBUCK+1
    int*   gcur    = boff + NBUCK + 1;             // NBUCK

    hipMemsetAsync(gbcount, 0, NBUCK * sizeof(int), stream);
    k_init_x<<<(NODES * DD / 4 + 255) / 256, 256, 0, stream>>>(eu, ei, x);
    k_gather<<<(3 * BB * 64 + 255) / 256, 256, 0, stream>>>(x, su, oi, ui, out, 0);

    k_cnt<<<NPB, 512, 0, stream>>>(edge_row, gbcount);
    k_bscan<<<1, 512, 0, stream>>>(gbcount, boff, gcur);
    k_place<<<NPB, 512, 0, stream>>>(edge_row, edge_col, edge_val, gcur, bulk);

    for (int l = 0; l < 3; ++l) {
        k_pspmm<<<NBUCK, 1024, 0, stream>>>(boff, bulk, x, lie);
        k_gemm<<<(NODES + 63) / 64, 256, 0, stream>>>(x, lie,
                                                      W1 + l * 4096, W2 + l * 4096,
                                                      b1 + l * 64,  b2 + l * 64);
        k_gather<<<(3 * BB * 64 + 255) / 256, 256, 0, stream>>>(x, su, oi, ui, out, l + 1);
    }
}

// Round 4
// 638.953 us; speedup vs baseline: 7.1453x; 7.1453x over previous
//
#include <hip/hip_runtime.h>

#define NN    60000
#define NODES 100000
#define DD    64
#define NNZ   3200000
#define BB    1024
#define NEG   0.2f
#define RPB   256                        // rows per bucket
#define NBUCK 391                        // ceil(NODES/RPB)
#define EPB   8192                       // edges per sort block
#define NPB   ((NNZ + EPB - 1) / EPB)    // 391
#define BCAP  9216                       // LDS edge capacity in k_csr (mean 8192, +11 sigma)

// ---------------------------------------------------------------- init x = concat(eu, ei)
__global__ __launch_bounds__(256) void k_init_x(const float* __restrict__ eu,
                                                const float* __restrict__ ei,
                                                float* __restrict__ x) {
    int i = blockIdx.x * 256 + threadIdx.x;          // float4 index
    const int TOT = NODES * DD / 4;
    if (i >= TOT) return;
    const int UE = NN * DD / 4;
    float4 v = (i < UE) ? ((const float4*)eu)[i] : ((const float4*)ei)[i - UE];
    ((float4*)x)[i] = v;
}

// ---------------------------------------------------------------- bucket counts
__global__ __launch_bounds__(512) void k_cnt(const int* __restrict__ row,
                                             int* __restrict__ gbcount) {
    __shared__ int h[NBUCK];
    int t = threadIdx.x;
    if (t < NBUCK) h[t] = 0;
    __syncthreads();
    int base = blockIdx.x * EPB;
    int n = min(EPB, NNZ - base);
    for (int k = t; k < n; k += 512) atomicAdd(&h[row[base + k] >> 8], 1);
    __syncthreads();
    if (t < NBUCK && h[t]) atomicAdd(&gbcount[t], h[t]);
}

// ---------------------------------------------------------------- bucket offsets (1 block)
__global__ __launch_bounds__(512) void k_bscan(const int* __restrict__ gbcount,
                                               int* __restrict__ boff,
                                               int* __restrict__ gcur) {
    __shared__ int s[512];
    int t = threadIdx.x;
    int v = (t < NBUCK) ? gbcount[t] : 0;
    s[t] = v;
    __syncthreads();
    for (int off = 1; off < 512; off <<= 1) {
        int u = (t >= off) ? s[t - off] : 0;
        __syncthreads();
        s[t] += u;
        __syncthreads();
    }
    int ex = s[t] - v;
    if (t < NBUCK) { boff[t] = ex; gcur[t] = ex; }
    if (t == NBUCK) boff[NBUCK] = ex;   // == NNZ
}

// ---------------------------------------------------------------- bucket sort -> bulk
// block-local LDS counting sort -> contiguous ascending global write runs
__global__ __launch_bounds__(512) void k_place(const int* __restrict__ row,
                                               const int* __restrict__ col,
                                               const float* __restrict__ val,
                                               int* __restrict__ gcur,
                                               int2* __restrict__ bulk) {
    __shared__ int rows_l[EPB];                // 32 KB
    __shared__ unsigned short perm[EPB];       // 16 KB
    __shared__ int h[NBUCK], bloc[NBUCK], bcur[NBUCK], gseg[NBUCK];
    __shared__ int sc[512];
    int t = threadIdx.x;
    if (t < NBUCK) h[t] = 0;
    __syncthreads();
    int base = blockIdx.x * EPB;
    int n = min(EPB, NNZ - base);
    for (int k = t; k < n; k += 512) {
        int r = row[base + k];
        rows_l[k] = r;
        atomicAdd(&h[r >> 8], 1);
    }
    __syncthreads();
    {
        int v = (t < NBUCK) ? h[t] : 0;
        sc[t] = v;
        __syncthreads();
        for (int off = 1; off < 512; off <<= 1) {
            int u = (t >= off) ? sc[t - off] : 0;
            __syncthreads();
            sc[t] += u;
            __syncthreads();
        }
        if (t < NBUCK) {
            int ex = sc[t] - v;
            bloc[t] = ex;
            bcur[t] = ex;
            gseg[t] = v ? atomicAdd(&gcur[t], v) : 0;
        }
    }
    __syncthreads();
    for (int k = t; k < n; k += 512) {
        int p = atomicAdd(&bcur[rows_l[k] >> 8], 1);
        perm[p] = (unsigned short)k;
    }
    __syncthreads();
    for (int j = t; j < n; j += 512) {
        int k = perm[j];
        int r = rows_l[k];
        int b8 = r >> 8;
        int addr = gseg[b8] + (j - bloc[b8]);
        bulk[addr] = make_int2(((r & 255) << 17) | col[base + k],
                               __float_as_int(val[base + k]));
    }
}

// ---------------------------------------------------------------- per-bucket row sort (in place)
// one block per bucket: LDS counting sort by local row, write back to same dense
// segment (single-writer 65 KB region), emit per-row (start,end) into rsd.
__global__ __launch_bounds__(512) void k_csr(const int* __restrict__ boff,
                                             int2* __restrict__ bulk,
                                             int2* __restrict__ rsd) {
    __shared__ int2 eds[BCAP];                 // 72 KB
    __shared__ int h[RPB], sc[RPB], bcur[RPB];
    int b = blockIdx.x, t = threadIdx.x;
    int lo = boff[b], hi = boff[b + 1];
    int n = hi - lo;
    if (t < RPB) h[t] = 0;
    __syncthreads();
    for (int i = t; i < n; i += 512) {
        int2 ed = bulk[lo + i];
        eds[i] = ed;
        atomicAdd(&h[ed.x >> 17], 1);
    }
    __syncthreads();
    // exclusive scan over 256 row-counters (uniform barrier structure)
    int v = 0;
    if (t < RPB) { v = h[t]; sc[t] = v; }
    __syncthreads();
    for (int off = 1; off < RPB; off <<= 1) {
        int u = 0;
        if (t < RPB && t >= off) u = sc[t - off];
        __syncthreads();
        if (t < RPB) sc[t] += u;
        __syncthreads();
    }
    if (t < RPB) {
        int ex = sc[t] - v;
        bcur[t] = ex;
        int r = b * RPB + t;
        if (r < NODES) rsd[r] = make_int2(lo + ex, lo + ex + v);
    }
    __syncthreads();
    // scatter back in sorted order, stripping the row bits
    for (int i = t; i < n; i += 512) {
        int2 ed = eds[i];
        int p = atomicAdd(&bcur[ed.x >> 17], 1);
        bulk[lo + p] = make_int2(ed.x & 0x1FFFF, ed.y);
    }
}

// ---------------------------------------------------------------- pull SpMM: one wave / row,
// NO shuffles: all lanes load the same cv entry (HW broadcast), 8 gathers in flight
__global__ __launch_bounds__(256) void k_spmm(const int2* __restrict__ rsd,
                                              const int2* __restrict__ cv,
                                              const float* __restrict__ x,
                                              float* __restrict__ lie) {
    int w    = (blockIdx.x * 256 + threadIdx.x) >> 6;
    int lane = threadIdx.x & 63;
    if (w >= NODES) return;
    int2 se = rsd[w];
    int s = se.x, e = se.y;
    float acc = 0.f;
    int g = s;
    for (; g + 8 <= e; g += 8) {
        int2 e0 = cv[g],     e1 = cv[g + 1], e2 = cv[g + 2], e3 = cv[g + 3];
        int2 e4 = cv[g + 4], e5 = cv[g + 5], e6 = cv[g + 6], e7 = cv[g + 7];
        float x0 = x[e0.x * DD + lane];
        float x1 = x[e1.x * DD + lane];
        float x2 = x[e2.x * DD + lane];
        float x3 = x[e3.x * DD + lane];
        float x4 = x[e4.x * DD + lane];
        float x5 = x[e5.x * DD + lane];
        float x6 = x[e6.x * DD + lane];
        float x7 = x[e7.x * DD + lane];
        acc = fmaf(__int_as_float(e0.y), x0, acc);
        acc = fmaf(__int_as_float(e1.y), x1, acc);
        acc = fmaf(__int_as_float(e2.y), x2, acc);
        acc = fmaf(__int_as_float(e3.y), x3, acc);
        acc = fmaf(__int_as_float(e4.y), x4, acc);
        acc = fmaf(__int_as_float(e5.y), x5, acc);
        acc = fmaf(__int_as_float(e6.y), x6, acc);
        acc = fmaf(__int_as_float(e7.y), x7, acc);
    }
    for (; g < e; ++g) {
        int2 ed = cv[g];
        acc = fmaf(__int_as_float(ed.y), x[ed.x * DD + lane], acc);
    }
    lie[w * DD + lane] = acc;
}

// ---------------------------------------------------------------- fused layer GEMM
__global__ __launch_bounds__(256) void k_gemm(float* __restrict__ x,
                                              const float* __restrict__ lie,
                                              const float* __restrict__ W1,
                                              const float* __restrict__ W2,
                                              const float* __restrict__ b1,
                                              const float* __restrict__ b2) {
    __shared__ float A1[64 * 64];
    __shared__ float A2[64 * 64];
    __shared__ float Ws1[64 * 64];
    __shared__ float Ws2[64 * 64];

    const int t = threadIdx.x;
    const int row0 = blockIdx.x * 64;

    {
        const float4* w1v = (const float4*)W1;
        const float4* w2v = (const float4*)W2;
        float4* s1v = (float4*)Ws1;
        float4* s2v = (float4*)Ws2;
#pragma unroll
        for (int q = 0; q < 4; ++q) {
            s1v[q * 256 + t] = w1v[q * 256 + t];
            s2v[q * 256 + t] = w2v[q * 256 + t];
        }
    }
#pragma unroll
    for (int q = 0; q < 4; ++q) {
        int f4 = q * 256 + t;
        int rl = f4 >> 4;
        int c4 = f4 & 15;
        int gr = row0 + rl;
        float4 lv = make_float4(0.f, 0.f, 0.f, 0.f);
        float4 xv = make_float4(0.f, 0.f, 0.f, 0.f);
        if (gr < NODES) {
            lv = *(const float4*)&lie[gr * DD + c4 * 4];
            xv = *(const float4*)&x[gr * DD + c4 * 4];
        }
        int sg = c4 ^ (rl & 15);
        ((float4*)A1)[rl * 16 + sg] = lv;
        ((float4*)A2)[rl * 16 + sg] = make_float4(lv.x * xv.x, lv.y * xv.y,
                                                  lv.z * xv.z, lv.w * xv.w);
    }
    __syncthreads();

    const int tx = t & 15;
    const int ty = t >> 4;
    float bs[4];
    {
        float4 bb1 = *(const float4*)&b1[tx * 4];
        float4 bb2 = *(const float4*)&b2[tx * 4];
        bs[0] = bb1.x + bb2.x; bs[1] = bb1.y + bb2.y;
        bs[2] = bb1.z + bb2.z; bs[3] = bb1.w + bb2.w;
    }
    float acc[4][4];
#pragma unroll
    for (int i = 0; i < 4; ++i)
#pragma unroll
        for (int j = 0; j < 4; ++j) acc[i][j] = bs[j];

    for (int k4 = 0; k4 < 16; ++k4) {
        float4 a1[4], a2[4];
#pragma unroll
        for (int i = 0; i < 4; ++i) {
            int r = ty * 4 + i;
            int sg = k4 ^ (r & 15);
            a1[i] = ((const float4*)A1)[r * 16 + sg];
            a2[i] = ((const float4*)A2)[r * 16 + sg];
        }
#pragma unroll
        for (int kk = 0; kk < 4; ++kk) {
            float4 w1 = ((const float4*)Ws1)[(k4 * 4 + kk) * 16 + tx];
            float4 w2 = ((const float4*)Ws2)[(k4 * 4 + kk) * 16 + tx];
#pragma unroll
            for (int i = 0; i < 4; ++i) {
                float av1 = (&a1[i].x)[kk];
                float av2 = (&a2[i].x)[kk];
                acc[i][0] = fmaf(av1, w1.x, fmaf(av2, w2.x, acc[i][0]));
                acc[i][1] = fmaf(av1, w1.y, fmaf(av2, w2.y, acc[i][1]));
                acc[i][2] = fmaf(av1, w1.z, fmaf(av2, w2.z, acc[i][2]));
                acc[i][3] = fmaf(av1, w1.w, fmaf(av2, w2.w, acc[i][3]));
            }
        }
    }
#pragma unroll
    for (int i = 0; i < 4; ++i) {
        int gr = row0 + ty * 4 + i;
        if (gr < NODES) {
            float4 o;
            o.x = acc[i][0] >= 0.f ? acc[i][0] : NEG * acc[i][0];
            o.y = acc[i][1] >= 0.f ? acc[i][1] : NEG * acc[i][1];
            o.z = acc[i][2] >= 0.f ? acc[i][2] : NEG * acc[i][2];
            o.w = acc[i][3] >= 0.f ? acc[i][3] : NEG * acc[i][3];
            *(float4*)&x[gr * DD + tx * 4] = o;
        }
    }
}

// ---------------------------------------------------------------- gather layer repr into output
__global__ __launch_bounds__(256) void k_gather(const float* __restrict__ x,
                                                const int* __restrict__ su,
                                                const int* __restrict__ oi,
                                                const int* __restrict__ ui,
                                                float* __restrict__ out, int layer) {
    int w    = (blockIdx.x * 256 + threadIdx.x) >> 6;
    int lane = threadIdx.x & 63;
    if (w >= 3 * BB) return;
    int g = w >> 10, b = w & 1023;
    int node = (g == 0) ? su[b] : (NN + ((g == 1) ? oi[b] : ui[b]));
    out[w * 256 + layer * 64 + lane] = x[node * DD + lane];
}

// ---------------------------------------------------------------- launch
extern "C" void kernel_launch(void* const* d_in, const int* in_sizes, int n_in,
                              void* d_out, int out_size, void* d_ws, size_t ws_size,
                              hipStream_t stream) {
    const int*   edge_row = (const int*)d_in[0];
    const int*   edge_col = (const int*)d_in[1];
    const float* edge_val = (const float*)d_in[2];
    const float* eu = (const float*)d_in[3];
    const float* ei = (const float*)d_in[4];
    const float* W1 = (const float*)d_in[5];
    const float* W2 = (const float*)d_in[6];
    const float* b1 = (const float*)d_in[7];
    const float* b2 = (const float*)d_in[8];
    const int*   su = (const int*)d_in[9];
    const int*   oi = (const int*)d_in[10];
    const int*   ui = (const int*)d_in[11];
    float* out = (float*)d_out;

    // workspace carve (~77.6 MB)
    float* x       = (float*)d_ws;                 // 6.4M f
    float* lie     = x + NODES * DD;               // 6.4M f
    int2*  bulk    = (int2*)(lie + NODES * DD);    // NNZ int2 (sorted in place)
    int*   gbcount = (int*)(bulk + NNZ);           // NBUCK
    int*   boff    = gbcount + NBUCK;              // NBUCK+1
    int*   gcur    = boff + NBUCK + 1;             // NBUCK
    int2*  rsd     = (int2*)(gcur + NBUCK);        // NODES int2 (800 KB)

    hipMemsetAsync(gbcount, 0, NBUCK * sizeof(int), stream);
    k_init_x<<<(NODES * DD / 4 + 255) / 256, 256, 0, stream>>>(eu, ei, x);
    k_gather<<<(3 * BB * 64 + 255) / 256, 256, 0, stream>>>(x, su, oi, ui, out, 0);

    k_cnt<<<NPB, 512, 0, stream>>>(edge_row, gbcount);
    k_bscan<<<1, 512, 0, stream>>>(gbcount, boff, gcur);
    k_place<<<NPB, 512, 0, stream>>>(edge_row, edge_col, edge_val, gcur, bulk);
    k_csr<<<NBUCK, 512, 0, stream>>>(boff, bulk, rsd);

    for (int l = 0; l < 3; ++l) {
        k_spmm<<<(NODES * 64 + 255) / 256, 256, 0, stream>>>(rsd, bulk, x, lie);
        k_gemm<<<(NODES + 63) / 64, 256, 0, stream>>>(x, lie,
                                                      W1 + l * 4096, W2 + l * 4096,
                                                      b1 + l * 64,  b2 + l * 64);
        k_gather<<<(3 * BB * 64 + 255) / 256, 256, 0, stream>>>(x, su, oi, ui, out, l + 1);
    }
}